// Round 1
// baseline (90.680 us; speedup 1.0000x reference)
//
#include <hip/hip_runtime.h>
#include <math.h>

// Backflow: out[i] = xi(|x_i|,t)*x_i + sum_j eta(|x_i-x_j|,t)*(x_i-x_j)
// t scalar -> eta(r) is 1-D: dense table (513 pts over [0,16], linear interp,
// per-pair err ~1e-10) replaces 1M MLP evals. Fixed harness overhead ~72us
// (268MB ws re-poison @85% HBM + restores); controllable kernel time was
// ~13.5us across two serial launches (k1 table+xi, k2 pair loop).
//
// R8: single-launch fusion via producer/consumer blocks + device-scope flag
// handshake. Blocks 0..64 compute the eta table and release-publish it;
// blocks 65..192 compute xi(|x_i|) for 2 rows/wave IN REGISTERS (no ws
// round-trip) + stage x into LDS concurrently, then acquire-spin on the 65
// producer flags (expected ~0 wait: consumer pre-spin work >= producer work),
// stage the 2KB table, and run both rows' pair loops sharing x_j LDS reads.
// Saves one dispatch + the serial k1->k2 round-trip (~5-7us predicted).
//
// Poison-safe handshake: ws is re-poisoned each iter with an UNKNOWN pattern,
// so no counter (unknown init). Per-producer MAGIC flags instead; a
// poison==MAGIC collision makes consumers read garbage -> absmax fails
// VISIBLY (fallback then: hipMemsetAsync a zero flag before launch).
// Deadlock-free: 193 blocks <= 256 CUs, ~34KB LDS, 1 block/CU -> all blocks
// co-resident; producers always progress.
// R4/R6 spill failure dodged with __launch_bounds__(256,1): we only need
// 1 block/CU, so un-cap the register allocator.

#define TABLE_N 512
#define RMAX 16.0f
#define NPART 1024
#define EBLK 65                   // eta producer blocks: 65*8 = 520 >= 513 evals
#define XBLK 128                  // consumer blocks: 128 * (4 waves * 2 rows) = 1024 rows
#define DELTA (RMAX / (float)TABLE_N)
// ws float layout: table[0..516) | flags (u32) at word 1024..1089
#define FLAG_OFF 1024
#define FLAG_MAGIC 0x9E3779B9u

__device__ __forceinline__ float sp_fast(float v) {
    // softplus; preacts are tame here (|v| < ~6), no range fixups needed
    return __logf(1.f + __expf(v));
}

__global__ __launch_bounds__(256, 1) void k_fused(
    const float* __restrict__ x, const float* __restrict__ t_ptr,
    const float* __restrict__ xiW1, const float* __restrict__ xib1,
    const float* __restrict__ xiW2, const float* __restrict__ xib2,
    const float* __restrict__ xiW3, const float* __restrict__ xib3,
    const float* __restrict__ eW1,  const float* __restrict__ eb1,
    const float* __restrict__ eW2,  const float* __restrict__ eb2,
    const float* __restrict__ eW3,  const float* __restrict__ eb3,
    float* __restrict__ ws, float* __restrict__ out)
{
    __shared__ __align__(16) float w2s[4096];    // W2 (64x64), 16 KB
    __shared__ __align__(16) float w1s[128];
    __shared__ __align__(16) float b1s[64];
    __shared__ __align__(16) float b2s[64];
    __shared__ __align__(16) float w3s[64];
    __shared__ __align__(16) float hbuf[4][128]; // per-wave h for the pair
    __shared__ __align__(16) float xsoa[3 * NPART];
    __shared__ __align__(16) float tab[516];

    const int tid = threadIdx.x;
    const int b   = blockIdx.x;
    const bool tb = (b < EBLK);   // table-producer block?

    const float* __restrict__ W1 = tb ? eW1 : xiW1;
    const float* __restrict__ B1 = tb ? eb1 : xib1;
    const float* __restrict__ W2 = tb ? eW2 : xiW2;
    const float* __restrict__ B2 = tb ? eb2 : xib2;
    const float* __restrict__ W3 = tb ? eW3 : xiW3;

    {   // bulk-stage weights into LDS (both paths)
        const float4* src = (const float4*)W2;
        float4* dst = (float4*)w2s;
        #pragma unroll
        for (int i2 = 0; i2 < 4; ++i2) dst[tid + 256 * i2] = src[tid + 256 * i2];
        if (tid < 128)      w1s[tid]       = W1[tid];
        else if (tid < 192) b1s[tid - 128] = B1[tid - 128];
        else                b2s[tid - 192] = B2[tid - 192];
        if (tid < 64)       w3s[tid]       = W3[tid];
    }
    if (!tb) {   // consumers also stage x (straight interleaved copy)
        const float4* src = (const float4*)x;
        float4* dst = (float4*)xsoa;
        #pragma unroll
        for (int i2 = 0; i2 < 3; ++i2) dst[tid + 256 * i2] = src[tid + 256 * i2];
    }

    const float t  = t_ptr[0];
    const float B3 = tb ? eb3[0] : xib3[0];
    const int lane = tid & 63;
    const int w    = tid >> 6;
    const int e0   = (tb ? 8 * b : 8 * (b - EBLK)) + 2 * w;  // table idx or row idx
    const int e1   = e0 + 1;

    float r0, r1;
    if (tb) {
        r0 = (float)e0 * DELTA;              // e>512 computed, write-guarded
        r1 = (float)e1 * DELTA;
    } else {
        float ax_ = x[3 * e0], ay_ = x[3 * e0 + 1], az_ = x[3 * e0 + 2];
        float bx_ = x[3 * e1], by_ = x[3 * e1 + 1], bz_ = x[3 * e1 + 2];
        r0 = sqrtf(fmaf(ax_, ax_, fmaf(ay_, ay_, az_ * az_)));
        r1 = sqrtf(fmaf(bx_, bx_, fmaf(by_, by_, bz_ * bz_)));
    }
    __syncthreads();

    // ---- MLP eval pair (identical structure to proven k1) ----
    // phase A: lane k -> h_k for both evals (wave-private LDS, no barrier)
    const float w1a = w1s[lane], w1b = w1s[64 + lane], b1v = b1s[lane];
    hbuf[w][lane]      = sp_fast(fmaf(r0, w1a, fmaf(t, w1b, b1v)));
    hbuf[w][64 + lane] = sp_fast(fmaf(r1, w1a, fmaf(t, w1b, b1v)));
    // phase B: lane m -> z_m; W2 LDS reads stride-1 (conflict-free), shared
    float z0 = b2s[lane], z1 = z0;
    #pragma unroll
    for (int k = 0; k < 64; k += 4) {
        float4 ha = *(const float4*)&hbuf[w][k];
        float4 hb = *(const float4*)&hbuf[w][64 + k];
        float wa  = w2s[k * 64 + lane];
        float wbv = w2s[(k + 1) * 64 + lane];
        float wc  = w2s[(k + 2) * 64 + lane];
        float wd  = w2s[(k + 3) * 64 + lane];
        z0 = fmaf(ha.x, wa,  z0); z1 = fmaf(hb.x, wa,  z1);
        z0 = fmaf(ha.y, wbv, z0); z1 = fmaf(hb.y, wbv, z1);
        z0 = fmaf(ha.z, wc,  z0); z1 = fmaf(hb.z, wc,  z1);
        z0 = fmaf(ha.w, wd,  z0); z1 = fmaf(hb.w, wd,  z1);
    }
    // epilogue: p_m = softplus(z_m)*W3[m], reduce across the wave
    float q0 = sp_fast(z0) * w3s[lane];
    float q1 = sp_fast(z1) * w3s[lane];
    #pragma unroll
    for (int off = 32; off > 0; off >>= 1) {
        q0 += __shfl_xor(q0, off);
        q1 += __shfl_xor(q1, off);
    }
    const float f0 = q0 + B3;   // all lanes hold the sum
    const float f1 = q1 + B3;

    if (tb) {
        // publish table slice, then release-flag this block done
        if (lane == 0) {
            if (e0 <= TABLE_N) ws[e0] = f0;
            if (e1 <= TABLE_N) ws[e1] = f1;
        }
        __syncthreads();                       // drains all 4 waves' stores
        if (tid == 0) {
            __threadfence();                   // agent-scope L2 writeback
            __hip_atomic_store((unsigned int*)ws + FLAG_OFF + b, FLAG_MAGIC,
                               __ATOMIC_RELEASE, __HIP_MEMORY_SCOPE_AGENT);
        }
        return;
    }

    // ---- consumer: wait for the 65 producer flags (expected ~0 wait) ----
    if (tid < EBLK) {
        const unsigned int* flags = (const unsigned int*)ws + FLAG_OFF;
        while (__hip_atomic_load(&flags[tid], __ATOMIC_ACQUIRE,
                                 __HIP_MEMORY_SCOPE_AGENT) != FLAG_MAGIC) {}
    }
    __syncthreads();
    {   // stage table (acquire above invalidated caches for the whole CU)
        const float4* ts = (const float4*)ws;
        float4* td = (float4*)tab;
        if (tid < 129) td[tid] = ts[tid];
    }
    __syncthreads();

    // ---- pair loops, rows e0 & e1 interleaved (share x_j LDS reads) ----
    const float xi0 = xsoa[3 * e0], yi0 = xsoa[3 * e0 + 1], zi0 = xsoa[3 * e0 + 2];
    const float xi1 = xsoa[3 * e1], yi1 = xsoa[3 * e1 + 1], zi1 = xsoa[3 * e1 + 2];
    float ax0 = 0.f, ay0 = 0.f, az0 = 0.f;
    float ax1 = 0.f, ay1 = 0.f, az1 = 0.f;
    const float scale = (float)TABLE_N / RMAX;     // 32
    #pragma unroll
    for (int it = 0; it < NPART / 64; ++it) {
        int j = it * 64 + lane;
        // stride-3 b32 reads: 2 lanes/bank (free)
        float xj = xsoa[3 * j], yj = xsoa[3 * j + 1], zj = xsoa[3 * j + 2];
        {   // row e0 (diagonal j==i: r=0 -> f*0 = 0)
            float dx = xi0 - xj, dy = yi0 - yj, dz = zi0 - zj;
            float r = sqrtf(fmaf(dx, dx, fmaf(dy, dy, dz * dz)));
            float u = fminf(r * scale, (float)TABLE_N - 0.001f);
            int i0 = (int)u;
            float fr = u - (float)i0;
            float t0 = tab[i0], t1v = tab[i0 + 1];
            float f = fmaf(fr, t1v - t0, t0);
            ax0 = fmaf(f, dx, ax0); ay0 = fmaf(f, dy, ay0); az0 = fmaf(f, dz, az0);
        }
        {   // row e1
            float dx = xi1 - xj, dy = yi1 - yj, dz = zi1 - zj;
            float r = sqrtf(fmaf(dx, dx, fmaf(dy, dy, dz * dz)));
            float u = fminf(r * scale, (float)TABLE_N - 0.001f);
            int i0 = (int)u;
            float fr = u - (float)i0;
            float t0 = tab[i0], t1v = tab[i0 + 1];
            float f = fmaf(fr, t1v - t0, t0);
            ax1 = fmaf(f, dx, ax1); ay1 = fmaf(f, dy, ay1); az1 = fmaf(f, dz, az1);
        }
    }
    #pragma unroll
    for (int off = 32; off > 0; off >>= 1) {
        ax0 += __shfl_xor(ax0, off); ay0 += __shfl_xor(ay0, off); az0 += __shfl_xor(az0, off);
        ax1 += __shfl_xor(ax1, off); ay1 += __shfl_xor(ay1, off); az1 += __shfl_xor(az1, off);
    }
    if (lane == 0) {   // fvals never left registers: single writer of out
        out[3 * e0]     = fmaf(f0, xi0, ax0);
        out[3 * e0 + 1] = fmaf(f0, yi0, ay0);
        out[3 * e0 + 2] = fmaf(f0, zi0, az0);
        out[3 * e1]     = fmaf(f1, xi1, ax1);
        out[3 * e1 + 1] = fmaf(f1, yi1, ay1);
        out[3 * e1 + 2] = fmaf(f1, zi1, az1);
    }
}

extern "C" void kernel_launch(void* const* d_in, const int* in_sizes, int n_in,
                              void* d_out, int out_size, void* d_ws, size_t ws_size,
                              hipStream_t stream) {
    const float* x     = (const float*)d_in[0];
    const float* t     = (const float*)d_in[1];
    const float* xiW1  = (const float*)d_in[2];
    const float* xib1  = (const float*)d_in[3];
    const float* xiW2  = (const float*)d_in[4];
    const float* xib2  = (const float*)d_in[5];
    const float* xiW3  = (const float*)d_in[6];
    const float* xib3  = (const float*)d_in[7];
    const float* eW1   = (const float*)d_in[8];
    const float* eb1   = (const float*)d_in[9];
    const float* eW2   = (const float*)d_in[10];
    const float* eb2   = (const float*)d_in[11];
    const float* eW3   = (const float*)d_in[12];
    const float* eb3   = (const float*)d_in[13];
    float* out = (float*)d_out;
    float* ws  = (float*)d_ws;

    k_fused<<<EBLK + XBLK, 256, 0, stream>>>(
        x, t, xiW1, xib1, xiW2, xib2, xiW3, xib3,
        eW1, eb1, eW2, eb2, eW3, eb3, ws, out);
}

// Round 2
// 86.814 us; speedup vs baseline: 1.0445x; 1.0445x over previous
//
#include <hip/hip_runtime.h>
#include <math.h>

// Backflow: out[i] = xi(|x_i|,t)*x_i + sum_j eta(|x_i-x_j|,t)*(x_i-x_j)
// t scalar -> eta(r) is 1-D: dense table (513 pts over [0,16], linear interp,
// per-pair err ~1e-10) replaces 1M MLP evals. Fixed harness overhead ~72us
// (268MB ws re-poison @85% HBM + restores).
//
// R8 FAILED (+5us vs two-kernel 85.5): fusion itself is fine, but the
// handshake was cache-maintenance-heavy: producer __threadfence() ->
// buffer_wbl2 (full L2 writeback, expensive right after the 268MB poison
// fill left L2s hot) and consumer ACQUIRE polls -> buffer_inv per iteration
// (128 blocks hammering invalidates while producers fetch weights).
//
// R9: same producer/consumer fusion, zero-cache-maintenance handshake:
//  - table published via agent-scope RELAXED atomic stores (sc1
//    write-through -> visible at coherence point, nothing dirty in L2,
//    no wbl2 anywhere);
//  - ordering store->flag comes free from __syncthreads() (compiler drains
//    vmcnt(0) per wave before s_barrier), then a RELAXED flag store;
//  - consumers poll with RELAXED agent loads (no buffer_inv) + s_sleep
//    backoff + defensive ACQUIRE every 32 iters (progress guarantee);
//  - table staged via relaxed agent scalar loads (2-3/thread, parallel).
// Deadlock-free: 193 blocks <= 256 CUs, all co-resident; producers never wait.
// Poison-safe: per-producer MAGIC flags; collision -> visible absmax failure.
// R4/R6 spill failure dodged with __launch_bounds__(256,1).

#define TABLE_N 512
#define RMAX 16.0f
#define NPART 1024
#define EBLK 65                   // eta producer blocks: 65*8 = 520 >= 513 evals
#define XBLK 128                  // consumer blocks: 128 * (4 waves * 2 rows) = 1024 rows
#define DELTA (RMAX / (float)TABLE_N)
// ws float layout: table[0..513) | flags (u32) at word 1024..1089
#define FLAG_OFF 1024
#define FLAG_MAGIC 0x9E3779B9u

__device__ __forceinline__ float sp_fast(float v) {
    // softplus; preacts are tame here (|v| < ~6), no range fixups needed
    return __logf(1.f + __expf(v));
}

__global__ __launch_bounds__(256, 1) void k_fused(
    const float* __restrict__ x, const float* __restrict__ t_ptr,
    const float* __restrict__ xiW1, const float* __restrict__ xib1,
    const float* __restrict__ xiW2, const float* __restrict__ xib2,
    const float* __restrict__ xiW3, const float* __restrict__ xib3,
    const float* __restrict__ eW1,  const float* __restrict__ eb1,
    const float* __restrict__ eW2,  const float* __restrict__ eb2,
    const float* __restrict__ eW3,  const float* __restrict__ eb3,
    float* __restrict__ ws, float* __restrict__ out)
{
    __shared__ __align__(16) float w2s[4096];    // W2 (64x64), 16 KB
    __shared__ __align__(16) float w1s[128];
    __shared__ __align__(16) float b1s[64];
    __shared__ __align__(16) float b2s[64];
    __shared__ __align__(16) float w3s[64];
    __shared__ __align__(16) float hbuf[4][128]; // per-wave h for the pair
    __shared__ __align__(16) float xsoa[3 * NPART];
    __shared__ __align__(16) float tab[516];

    const int tid = threadIdx.x;
    const int b   = blockIdx.x;
    const bool tb = (b < EBLK);   // table-producer block?

    const float* __restrict__ W1 = tb ? eW1 : xiW1;
    const float* __restrict__ B1 = tb ? eb1 : xib1;
    const float* __restrict__ W2 = tb ? eW2 : xiW2;
    const float* __restrict__ B2 = tb ? eb2 : xib2;
    const float* __restrict__ W3 = tb ? eW3 : xiW3;

    {   // bulk-stage weights into LDS (both paths)
        const float4* src = (const float4*)W2;
        float4* dst = (float4*)w2s;
        #pragma unroll
        for (int i2 = 0; i2 < 4; ++i2) dst[tid + 256 * i2] = src[tid + 256 * i2];
        if (tid < 128)      w1s[tid]       = W1[tid];
        else if (tid < 192) b1s[tid - 128] = B1[tid - 128];
        else                b2s[tid - 192] = B2[tid - 192];
        if (tid < 64)       w3s[tid]       = W3[tid];
    }
    if (!tb) {   // consumers also stage x (straight interleaved copy)
        const float4* src = (const float4*)x;
        float4* dst = (float4*)xsoa;
        #pragma unroll
        for (int i2 = 0; i2 < 3; ++i2) dst[tid + 256 * i2] = src[tid + 256 * i2];
    }

    const float t  = t_ptr[0];
    const float B3 = tb ? eb3[0] : xib3[0];
    const int lane = tid & 63;
    const int w    = tid >> 6;
    const int e0   = (tb ? 8 * b : 8 * (b - EBLK)) + 2 * w;  // table idx or row idx
    const int e1   = e0 + 1;

    float r0, r1;
    if (tb) {
        r0 = (float)e0 * DELTA;              // e>512 computed, write-guarded
        r1 = (float)e1 * DELTA;
    } else {
        float ax_ = x[3 * e0], ay_ = x[3 * e0 + 1], az_ = x[3 * e0 + 2];
        float bx_ = x[3 * e1], by_ = x[3 * e1 + 1], bz_ = x[3 * e1 + 2];
        r0 = sqrtf(fmaf(ax_, ax_, fmaf(ay_, ay_, az_ * az_)));
        r1 = sqrtf(fmaf(bx_, bx_, fmaf(by_, by_, bz_ * bz_)));
    }
    __syncthreads();

    // ---- MLP eval pair (identical structure to proven k1) ----
    // phase A: lane k -> h_k for both evals (wave-private LDS, no barrier)
    const float w1a = w1s[lane], w1b = w1s[64 + lane], b1v = b1s[lane];
    hbuf[w][lane]      = sp_fast(fmaf(r0, w1a, fmaf(t, w1b, b1v)));
    hbuf[w][64 + lane] = sp_fast(fmaf(r1, w1a, fmaf(t, w1b, b1v)));
    // phase B: lane m -> z_m; W2 LDS reads stride-1 (conflict-free), shared
    float z0 = b2s[lane], z1 = z0;
    #pragma unroll
    for (int k = 0; k < 64; k += 4) {
        float4 ha = *(const float4*)&hbuf[w][k];
        float4 hb = *(const float4*)&hbuf[w][64 + k];
        float wa  = w2s[k * 64 + lane];
        float wbv = w2s[(k + 1) * 64 + lane];
        float wc  = w2s[(k + 2) * 64 + lane];
        float wd  = w2s[(k + 3) * 64 + lane];
        z0 = fmaf(ha.x, wa,  z0); z1 = fmaf(hb.x, wa,  z1);
        z0 = fmaf(ha.y, wbv, z0); z1 = fmaf(hb.y, wbv, z1);
        z0 = fmaf(ha.z, wc,  z0); z1 = fmaf(hb.z, wc,  z1);
        z0 = fmaf(ha.w, wd,  z0); z1 = fmaf(hb.w, wd,  z1);
    }
    // epilogue: p_m = softplus(z_m)*W3[m], reduce across the wave
    float q0 = sp_fast(z0) * w3s[lane];
    float q1 = sp_fast(z1) * w3s[lane];
    #pragma unroll
    for (int off = 32; off > 0; off >>= 1) {
        q0 += __shfl_xor(q0, off);
        q1 += __shfl_xor(q1, off);
    }
    const float f0 = q0 + B3;   // all lanes hold the sum
    const float f1 = q1 + B3;

    if (tb) {
        // publish table slice with write-through (agent-relaxed) stores:
        // visible at the coherence point, nothing left dirty in L2.
        if (lane == 0) {
            if (e0 <= TABLE_N)
                __hip_atomic_store(&ws[e0], f0, __ATOMIC_RELAXED,
                                   __HIP_MEMORY_SCOPE_AGENT);
            if (e1 <= TABLE_N)
                __hip_atomic_store(&ws[e1], f1, __ATOMIC_RELAXED,
                                   __HIP_MEMORY_SCOPE_AGENT);
        }
        // __syncthreads drains vmcnt(0) per wave before s_barrier -> all
        // table stores COMPLETE before the flag store issues. No fence.
        __syncthreads();
        if (tid == 0) {
            __hip_atomic_store((unsigned int*)ws + FLAG_OFF + b, FLAG_MAGIC,
                               __ATOMIC_RELAXED, __HIP_MEMORY_SCOPE_AGENT);
        }
        return;
    }

    // ---- consumer: wait for the 65 producer flags (expected ~0 wait) ----
    if (tid < EBLK) {
        const unsigned int* fl = (const unsigned int*)ws + FLAG_OFF + tid;
        unsigned int v = __hip_atomic_load(fl, __ATOMIC_RELAXED,
                                           __HIP_MEMORY_SCOPE_AGENT);
        int it = 0;
        while (v != FLAG_MAGIC) {
            __builtin_amdgcn_s_sleep(1);   // polite backoff, no cache traffic
            // relaxed poll (sc1 read, no buffer_inv); defensive acquire every
            // 32 iters guarantees progress if relaxed visibility ever stalls
            v = ((++it & 31) == 0)
                  ? __hip_atomic_load(fl, __ATOMIC_ACQUIRE,
                                      __HIP_MEMORY_SCOPE_AGENT)
                  : __hip_atomic_load(fl, __ATOMIC_RELAXED,
                                      __HIP_MEMORY_SCOPE_AGENT);
        }
    }
    __syncthreads();
    {   // stage table via relaxed agent loads (coherence-point reads; the
        // producers' sc1 stores never sat dirty in any L2 -> no inv needed).
        float v0 = __hip_atomic_load(&ws[tid], __ATOMIC_RELAXED,
                                     __HIP_MEMORY_SCOPE_AGENT);
        float v1 = __hip_atomic_load(&ws[tid + 256], __ATOMIC_RELAXED,
                                     __HIP_MEMORY_SCOPE_AGENT);
        tab[tid]       = v0;
        tab[tid + 256] = v1;
        if (tid == 0)
            tab[512] = __hip_atomic_load(&ws[512], __ATOMIC_RELAXED,
                                         __HIP_MEMORY_SCOPE_AGENT);
        // tab[513..515] never read: interp index i0 <= 511.
    }
    __syncthreads();

    // ---- pair loops, rows e0 & e1 interleaved (share x_j LDS reads) ----
    const float xi0 = xsoa[3 * e0], yi0 = xsoa[3 * e0 + 1], zi0 = xsoa[3 * e0 + 2];
    const float xi1 = xsoa[3 * e1], yi1 = xsoa[3 * e1 + 1], zi1 = xsoa[3 * e1 + 2];
    float ax0 = 0.f, ay0 = 0.f, az0 = 0.f;
    float ax1 = 0.f, ay1 = 0.f, az1 = 0.f;
    const float scale = (float)TABLE_N / RMAX;     // 32
    #pragma unroll
    for (int it = 0; it < NPART / 64; ++it) {
        int j = it * 64 + lane;
        // stride-3 b32 reads: 2 lanes/bank (free)
        float xj = xsoa[3 * j], yj = xsoa[3 * j + 1], zj = xsoa[3 * j + 2];
        {   // row e0 (diagonal j==i: r=0 -> f*0 = 0)
            float dx = xi0 - xj, dy = yi0 - yj, dz = zi0 - zj;
            float r = sqrtf(fmaf(dx, dx, fmaf(dy, dy, dz * dz)));
            float u = fminf(r * scale, (float)TABLE_N - 0.001f);
            int i0 = (int)u;
            float fr = u - (float)i0;
            float t0 = tab[i0], t1v = tab[i0 + 1];
            float f = fmaf(fr, t1v - t0, t0);
            ax0 = fmaf(f, dx, ax0); ay0 = fmaf(f, dy, ay0); az0 = fmaf(f, dz, az0);
        }
        {   // row e1
            float dx = xi1 - xj, dy = yi1 - yj, dz = zi1 - zj;
            float r = sqrtf(fmaf(dx, dx, fmaf(dy, dy, dz * dz)));
            float u = fminf(r * scale, (float)TABLE_N - 0.001f);
            int i0 = (int)u;
            float fr = u - (float)i0;
            float t0 = tab[i0], t1v = tab[i0 + 1];
            float f = fmaf(fr, t1v - t0, t0);
            ax1 = fmaf(f, dx, ax1); ay1 = fmaf(f, dy, ay1); az1 = fmaf(f, dz, az1);
        }
    }
    #pragma unroll
    for (int off = 32; off > 0; off >>= 1) {
        ax0 += __shfl_xor(ax0, off); ay0 += __shfl_xor(ay0, off); az0 += __shfl_xor(az0, off);
        ax1 += __shfl_xor(ax1, off); ay1 += __shfl_xor(ay1, off); az1 += __shfl_xor(az1, off);
    }
    if (lane == 0) {   // fvals never left registers: single writer of out
        out[3 * e0]     = fmaf(f0, xi0, ax0);
        out[3 * e0 + 1] = fmaf(f0, yi0, ay0);
        out[3 * e0 + 2] = fmaf(f0, zi0, az0);
        out[3 * e1]     = fmaf(f1, xi1, ax1);
        out[3 * e1 + 1] = fmaf(f1, yi1, ay1);
        out[3 * e1 + 2] = fmaf(f1, zi1, az1);
    }
}

extern "C" void kernel_launch(void* const* d_in, const int* in_sizes, int n_in,
                              void* d_out, int out_size, void* d_ws, size_t ws_size,
                              hipStream_t stream) {
    const float* x     = (const float*)d_in[0];
    const float* t     = (const float*)d_in[1];
    const float* xiW1  = (const float*)d_in[2];
    const float* xib1  = (const float*)d_in[3];
    const float* xiW2  = (const float*)d_in[4];
    const float* xib2  = (const float*)d_in[5];
    const float* xiW3  = (const float*)d_in[6];
    const float* xib3  = (const float*)d_in[7];
    const float* eW1   = (const float*)d_in[8];
    const float* eb1   = (const float*)d_in[9];
    const float* eW2   = (const float*)d_in[10];
    const float* eb2   = (const float*)d_in[11];
    const float* eW3   = (const float*)d_in[12];
    const float* eb3   = (const float*)d_in[13];
    float* out = (float*)d_out;
    float* ws  = (float*)d_ws;

    k_fused<<<EBLK + XBLK, 256, 0, stream>>>(
        x, t, xiW1, xib1, xiW2, xib2, xiW3, xib3,
        eW1, eb1, eW2, eb2, eW3, eb3, ws, out);
}

// Round 3
// 85.151 us; speedup vs baseline: 1.0649x; 1.0195x over previous
//
#include <hip/hip_runtime.h>
#include <math.h>

// Backflow: out[i] = xi(|x_i|,t)*x_i + sum_j eta(|x_i-x_j|,t)*(x_i-x_j)
// t scalar -> eta(r) is 1-D: dense table (513 pts over [0,16], linear interp)
// replaces 1M MLP evals. Fixed harness overhead ~72us (268MB ws re-poison
// @85% HBM + restores). Controllable part: the kernel(s).
//
// R8 FAILED (90.7): fence-heavy handshake (wbl2 + per-poll buffer_inv).
// R9 (86.8): relaxed sc1 handshake fixed that (-3.9us) but fused still
// +1.3 vs two-kernel 85.5. Diagnosis: (1) 256-thr blocks = 4 waves/CU, no
// latency hiding during cold staging; (2) consumers ran 2 rows/wave ->
// pair-loop serial length 2x the old k2; (3) producer barrier+tid0 flag tail.
//
// R10: 512-thread blocks (8 waves/CU), consumers 1 row/wave (pair serial
// halved back to k2 shape), producers 16 evals/block with PER-WAVE flags
// (store entries -> s_waitcnt vmcnt(0) -> flag; no producer barrier).
// Grid = 33 producers + 128 consumers = 161 blocks <= 256 CUs: co-resident,
// deadlock-free. Handshake stays zero-cache-maintenance (relaxed agent sc1
// stores/loads; defensive acquire every 32 polls).
// Poison-safe: per-wave MAGIC flags; collision -> visible absmax failure.

#define TABLE_N 512
#define RMAX 16.0f
#define NPART 1024
#define PBLK 33                   // producer blocks: 33*16 = 528 >= 513 evals
#define XBLK 128                  // consumer blocks: 128 * 8 waves * 1 row = 1024 rows
#define NFLAGS 264                // 33 blocks * 8 waves
#define DELTA (RMAX / (float)TABLE_N)
// ws float layout: table[0..513) | flags (u32) at word 1024..1288
#define FLAG_OFF 1024
#define FLAG_MAGIC 0x9E3779B9u

__device__ __forceinline__ float sp_fast(float v) {
    // softplus; preacts are tame here (|v| < ~6), no range fixups needed
    return __logf(1.f + __expf(v));
}

__global__ __launch_bounds__(512, 1) void k_fused(
    const float* __restrict__ x, const float* __restrict__ t_ptr,
    const float* __restrict__ xiW1, const float* __restrict__ xib1,
    const float* __restrict__ xiW2, const float* __restrict__ xib2,
    const float* __restrict__ xiW3, const float* __restrict__ xib3,
    const float* __restrict__ eW1,  const float* __restrict__ eb1,
    const float* __restrict__ eW2,  const float* __restrict__ eb2,
    const float* __restrict__ eW3,  const float* __restrict__ eb3,
    float* __restrict__ ws, float* __restrict__ out)
{
    __shared__ __align__(16) float w2s[4096];    // W2 (64x64), 16 KB
    __shared__ __align__(16) float w1s[128];
    __shared__ __align__(16) float b1s[64];
    __shared__ __align__(16) float b2s[64];
    __shared__ __align__(16) float w3s[64];
    __shared__ __align__(16) float hbuf[8][128]; // per-wave h
    __shared__ __align__(16) float xsoa[3 * NPART];
    __shared__ __align__(16) float tab[516];

    const int tid = threadIdx.x;
    const int b   = blockIdx.x;
    const bool tb = (b < PBLK);   // table-producer block?

    const float* __restrict__ W1 = tb ? eW1 : xiW1;
    const float* __restrict__ B1 = tb ? eb1 : xib1;
    const float* __restrict__ W2 = tb ? eW2 : xiW2;
    const float* __restrict__ B2 = tb ? eb2 : xib2;
    const float* __restrict__ W3 = tb ? eW3 : xiW3;

    {   // bulk-stage weights into LDS: W2 = 1024 float4, 2 per thread
        const float4* src = (const float4*)W2;
        float4* dst = (float4*)w2s;
        dst[tid]       = src[tid];
        dst[tid + 512] = src[tid + 512];
        if (tid < 128)      w1s[tid]       = W1[tid];
        else if (tid < 192) b1s[tid - 128] = B1[tid - 128];
        else if (tid < 256) b2s[tid - 192] = B2[tid - 192];
        else if (tid < 320) w3s[tid - 256] = W3[tid - 256];
    }
    if (!tb) {   // consumers also stage x (768 float4, straight copy)
        const float4* src = (const float4*)x;
        float4* dst = (float4*)xsoa;
        dst[tid] = src[tid];
        if (tid < 256) dst[tid + 512] = src[tid + 512];
    }

    const float t  = t_ptr[0];
    const float B3 = tb ? eb3[0] : xib3[0];
    const int lane = tid & 63;
    const int w    = tid >> 6;
    __syncthreads();

    if (tb) {
        // ---- producer wave: 2 table entries, publish, per-wave flag ----
        const int e0 = 16 * b + 2 * w;           // e>512 computed, write-guarded
        const int e1 = e0 + 1;
        const float r0 = (float)e0 * DELTA;
        const float r1 = (float)e1 * DELTA;
        // phase A: lane k -> h_k for both evals (wave-private LDS, no barrier)
        const float w1a = w1s[lane], w1b = w1s[64 + lane], b1v = b1s[lane];
        hbuf[w][lane]      = sp_fast(fmaf(r0, w1a, fmaf(t, w1b, b1v)));
        hbuf[w][64 + lane] = sp_fast(fmaf(r1, w1a, fmaf(t, w1b, b1v)));
        // phase B: lane m -> z_m; W2 LDS reads stride-1 (conflict-free)
        float z0 = b2s[lane], z1 = z0;
        #pragma unroll
        for (int k = 0; k < 64; k += 4) {
            float4 ha = *(const float4*)&hbuf[w][k];
            float4 hb = *(const float4*)&hbuf[w][64 + k];
            float wa  = w2s[k * 64 + lane];
            float wbv = w2s[(k + 1) * 64 + lane];
            float wc  = w2s[(k + 2) * 64 + lane];
            float wd  = w2s[(k + 3) * 64 + lane];
            z0 = fmaf(ha.x, wa,  z0); z1 = fmaf(hb.x, wa,  z1);
            z0 = fmaf(ha.y, wbv, z0); z1 = fmaf(hb.y, wbv, z1);
            z0 = fmaf(ha.z, wc,  z0); z1 = fmaf(hb.z, wc,  z1);
            z0 = fmaf(ha.w, wd,  z0); z1 = fmaf(hb.w, wd,  z1);
        }
        float q0 = sp_fast(z0) * w3s[lane];
        float q1 = sp_fast(z1) * w3s[lane];
        #pragma unroll
        for (int off = 32; off > 0; off >>= 1) {
            q0 += __shfl_xor(q0, off);
            q1 += __shfl_xor(q1, off);
        }
        if (lane == 0) {
            // publish with write-through (agent-relaxed) stores: visible at
            // coherence point, nothing dirty in L2, no wbl2 anywhere.
            if (e0 <= TABLE_N)
                __hip_atomic_store(&ws[e0], q0 + B3, __ATOMIC_RELAXED,
                                   __HIP_MEMORY_SCOPE_AGENT);
            if (e1 <= TABLE_N)
                __hip_atomic_store(&ws[e1], q1 + B3, __ATOMIC_RELAXED,
                                   __HIP_MEMORY_SCOPE_AGENT);
            // order stores -> flag within this wave; no barrier, no fence insn
            asm volatile("s_waitcnt vmcnt(0)" ::: "memory");
            __hip_atomic_store((unsigned int*)ws + FLAG_OFF + 8 * b + w,
                               FLAG_MAGIC, __ATOMIC_RELAXED,
                               __HIP_MEMORY_SCOPE_AGENT);
        }
        return;
    }

    // ---- consumer: 1 row per wave ----
    const int i = 8 * (b - PBLK) + w;
    const float xi0 = xsoa[3 * i], yi0 = xsoa[3 * i + 1], zi0 = xsoa[3 * i + 2];
    const float r0 = sqrtf(fmaf(xi0, xi0, fmaf(yi0, yi0, zi0 * zi0)));

    // xi MLP, single eval per wave
    const float w1a = w1s[lane], w1b = w1s[64 + lane], b1v = b1s[lane];
    hbuf[w][lane] = sp_fast(fmaf(r0, w1a, fmaf(t, w1b, b1v)));
    float z0 = b2s[lane];
    #pragma unroll
    for (int k = 0; k < 64; k += 4) {
        float4 ha = *(const float4*)&hbuf[w][k];
        z0 = fmaf(ha.x, w2s[k * 64 + lane],       z0);
        z0 = fmaf(ha.y, w2s[(k + 1) * 64 + lane], z0);
        z0 = fmaf(ha.z, w2s[(k + 2) * 64 + lane], z0);
        z0 = fmaf(ha.w, w2s[(k + 3) * 64 + lane], z0);
    }
    float q0 = sp_fast(z0) * w3s[lane];
    #pragma unroll
    for (int off = 32; off > 0; off >>= 1) q0 += __shfl_xor(q0, off);
    const float fxi = q0 + B3;   // all lanes hold xi(|x_i|,t)

    // wait for the 264 producer-wave flags (expected ~0 wait)
    if (tid < NFLAGS) {
        const unsigned int* fl = (const unsigned int*)ws + FLAG_OFF + tid;
        unsigned int v = __hip_atomic_load(fl, __ATOMIC_RELAXED,
                                           __HIP_MEMORY_SCOPE_AGENT);
        int it = 0;
        while (v != FLAG_MAGIC) {
            __builtin_amdgcn_s_sleep(1);   // polite backoff, no cache traffic
            v = ((++it & 31) == 0)
                  ? __hip_atomic_load(fl, __ATOMIC_ACQUIRE,
                                      __HIP_MEMORY_SCOPE_AGENT)
                  : __hip_atomic_load(fl, __ATOMIC_RELAXED,
                                      __HIP_MEMORY_SCOPE_AGENT);
        }
    }
    __syncthreads();
    {   // stage table via relaxed agent loads (producers' sc1 stores never
        // sat dirty in any L2 -> no invalidate needed)
        tab[tid] = __hip_atomic_load(&ws[tid], __ATOMIC_RELAXED,
                                     __HIP_MEMORY_SCOPE_AGENT);
        if (tid == 0)
            tab[512] = __hip_atomic_load(&ws[512], __ATOMIC_RELAXED,
                                         __HIP_MEMORY_SCOPE_AGENT);
        // tab[513..515] never read: interp index i0 <= 511.
    }
    __syncthreads();

    // pair loop, 1 row/wave (k2-proven shape)
    float ax = 0.f, ay = 0.f, az = 0.f;
    const float scale = (float)TABLE_N / RMAX;     // 32
    #pragma unroll
    for (int it = 0; it < NPART / 64; ++it) {
        int j = it * 64 + lane;
        // stride-3 b32 reads: 2 lanes/bank (free)
        float dx = xi0 - xsoa[3 * j];
        float dy = yi0 - xsoa[3 * j + 1];
        float dz = zi0 - xsoa[3 * j + 2];
        float r = sqrtf(fmaf(dx, dx, fmaf(dy, dy, dz * dz)));
        float u = fminf(r * scale, (float)TABLE_N - 0.001f);
        int i0 = (int)u;
        float fr = u - (float)i0;
        float t0 = tab[i0], t1v = tab[i0 + 1];
        float f = fmaf(fr, t1v - t0, t0);     // diagonal j==i: r=0 -> f*0 = 0
        ax = fmaf(f, dx, ax);
        ay = fmaf(f, dy, ay);
        az = fmaf(f, dz, az);
    }
    #pragma unroll
    for (int off = 32; off > 0; off >>= 1) {
        ax += __shfl_xor(ax, off);
        ay += __shfl_xor(ay, off);
        az += __shfl_xor(az, off);
    }
    if (lane == 0) {   // single writer of out; fxi never left registers
        out[3 * i]     = fmaf(fxi, xi0, ax);
        out[3 * i + 1] = fmaf(fxi, yi0, ay);
        out[3 * i + 2] = fmaf(fxi, zi0, az);
    }
}

extern "C" void kernel_launch(void* const* d_in, const int* in_sizes, int n_in,
                              void* d_out, int out_size, void* d_ws, size_t ws_size,
                              hipStream_t stream) {
    const float* x     = (const float*)d_in[0];
    const float* t     = (const float*)d_in[1];
    const float* xiW1  = (const float*)d_in[2];
    const float* xib1  = (const float*)d_in[3];
    const float* xiW2  = (const float*)d_in[4];
    const float* xib2  = (const float*)d_in[5];
    const float* xiW3  = (const float*)d_in[6];
    const float* xib3  = (const float*)d_in[7];
    const float* eW1   = (const float*)d_in[8];
    const float* eb1   = (const float*)d_in[9];
    const float* eW2   = (const float*)d_in[10];
    const float* eb2   = (const float*)d_in[11];
    const float* eW3   = (const float*)d_in[12];
    const float* eb3   = (const float*)d_in[13];
    float* out = (float*)d_out;
    float* ws  = (float*)d_ws;

    k_fused<<<PBLK + XBLK, 512, 0, stream>>>(
        x, t, xiW1, xib1, xiW2, xib2, xiW3, xib3,
        eW1, eb1, eW2, eb2, eW3, eb3, ws, out);
}

// Round 4
// 84.829 us; speedup vs baseline: 1.0690x; 1.0038x over previous
//
#include <hip/hip_runtime.h>
#include <math.h>

// Backflow: out[i] = xi(|x_i|,t)*x_i + sum_j eta(|x_i-x_j|,t)*(x_i-x_j)
// t scalar -> eta(r) is 1-D: dense table (513 pts over [0,16], linear interp)
// replaces 1M MLP evals. Fixed harness overhead ~72us (268MB ws re-poison
// @85% HBM + ~dozens of small restore dispatches). Controllable: the kernel.
//
// R8 FAILED (90.7): fence-heavy handshake (wbl2 + per-poll buffer_inv).
// R9 (86.8): relaxed sc1 handshake (no cache maintenance) fixed that.
// R10 (85.15): 512-thr blocks (8 waves/CU), 1 row/wave consumers, per-wave
// producer flags. Beat two-kernel anchor (85.5) but only by 0.35us.
//
// R11 theory: producer CUs are LDS-port-bound in MLP phase B (2xb128 +
// 4xb32 per k-iter x 16 x 8 waves ~ 9Kcyc ~ 3.8us/CU) and sit on the
// consumer critical path; 95 CUs were idle. Also consumer pair loop pays
// 3xb32 + 2 divergent gathers per iter AFTER the handshake.
// Changes: (1) 65 producer blocks x 1 eval/wave (halves producer LDS
// contention); (2) table stored as float2 pairs tab2[i]=(T[i],T[i+1]) ->
// single b64 gather in pair loop; (3) x packed as float4 in LDS -> single
// b128 read per pair iter. Handshake unchanged (relaxed sc1 stores/loads,
// per-wave MAGIC flags, s_waitcnt vmcnt(0) orders store->flag in-wave).
// Grid = 65 + 128 = 193 <= 256 CUs: co-resident, producers never wait ->
// deadlock-free. Poison-safe: MAGIC flags; collision -> visible failure.

#define TABLE_N 512
#define RMAX 16.0f
#define NPART 1024
#define PBLK 65                   // producer blocks: 65*8 waves*1 eval = 520 >= 513
#define XBLK 128                  // consumer blocks: 128 * 8 waves * 1 row = 1024 rows
#define NFLAGS 520                // 65 blocks * 8 waves
#define DELTA (RMAX / (float)TABLE_N)
// ws float layout: table[0..513) | flags (u32) at word 1024..1544
#define FLAG_OFF 1024
#define FLAG_MAGIC 0x9E3779B9u

__device__ __forceinline__ float sp_fast(float v) {
    // softplus; preacts are tame here (|v| < ~6), no range fixups needed
    return __logf(1.f + __expf(v));
}

__global__ __launch_bounds__(512, 1) void k_fused(
    const float* __restrict__ x, const float* __restrict__ t_ptr,
    const float* __restrict__ xiW1, const float* __restrict__ xib1,
    const float* __restrict__ xiW2, const float* __restrict__ xib2,
    const float* __restrict__ xiW3, const float* __restrict__ xib3,
    const float* __restrict__ eW1,  const float* __restrict__ eb1,
    const float* __restrict__ eW2,  const float* __restrict__ eb2,
    const float* __restrict__ eW3,  const float* __restrict__ eb3,
    float* __restrict__ ws, float* __restrict__ out)
{
    __shared__ __align__(16) float w2s[4096];    // W2 (64x64), 16 KB
    __shared__ __align__(16) float w1s[128];
    __shared__ __align__(16) float b1s[64];
    __shared__ __align__(16) float b2s[64];
    __shared__ __align__(16) float w3s[64];
    __shared__ __align__(16) float hbuf[8][64];  // per-wave h (1 eval)
    __shared__ __align__(16) float4 x4[NPART];   // padded (x,y,z,0), 16 KB
    __shared__ __align__(16) float tab[516];
    __shared__ __align__(16) float2 tab2[513];   // (T[i], T[i+1]) pairs

    const int tid = threadIdx.x;
    const int b   = blockIdx.x;
    const bool tb = (b < PBLK);   // table-producer block?

    const float* __restrict__ W1 = tb ? eW1 : xiW1;
    const float* __restrict__ B1 = tb ? eb1 : xib1;
    const float* __restrict__ W2 = tb ? eW2 : xiW2;
    const float* __restrict__ B2 = tb ? eb2 : xib2;
    const float* __restrict__ W3 = tb ? eW3 : xiW3;

    {   // bulk-stage weights into LDS: W2 = 1024 float4, 2 per thread
        const float4* src = (const float4*)W2;
        float4* dst = (float4*)w2s;
        dst[tid]       = src[tid];
        dst[tid + 512] = src[tid + 512];
        if (tid < 128)      w1s[tid]       = W1[tid];
        else if (tid < 192) b1s[tid - 128] = B1[tid - 128];
        else if (tid < 256) b2s[tid - 192] = B2[tid - 192];
        else if (tid < 320) w3s[tid - 256] = W3[tid - 256];
    }
    if (!tb) {   // consumers stage x repacked into padded float4
        #pragma unroll
        for (int j = tid; j < NPART; j += 512) {
            float a = x[3 * j], c = x[3 * j + 1], d = x[3 * j + 2];
            x4[j] = make_float4(a, c, d, 0.f);
        }
    }

    const float t  = t_ptr[0];
    const float B3 = tb ? eb3[0] : xib3[0];
    const int lane = tid & 63;
    const int w    = tid >> 6;
    __syncthreads();

    if (tb) {
        // ---- producer wave: ONE table entry, publish, per-wave flag ----
        const int e = 8 * b + w;                 // e>512 computed, write-guarded
        const float r0 = (float)e * DELTA;
        // phase A: lane k -> h_k (wave-private LDS, no barrier)
        hbuf[w][lane] = sp_fast(fmaf(r0, w1s[lane], fmaf(t, w1s[64 + lane], b1s[lane])));
        // phase B: lane m -> z_m; ha reads are LDS broadcasts (same addr),
        // w2s row reads stride-1 conflict-free
        float z0 = b2s[lane];
        #pragma unroll
        for (int k = 0; k < 64; k += 4) {
            float4 ha = *(const float4*)&hbuf[w][k];
            z0 = fmaf(ha.x, w2s[k * 64 + lane],       z0);
            z0 = fmaf(ha.y, w2s[(k + 1) * 64 + lane], z0);
            z0 = fmaf(ha.z, w2s[(k + 2) * 64 + lane], z0);
            z0 = fmaf(ha.w, w2s[(k + 3) * 64 + lane], z0);
        }
        float q0 = sp_fast(z0) * w3s[lane];
        #pragma unroll
        for (int off = 32; off > 0; off >>= 1) q0 += __shfl_xor(q0, off);
        if (lane == 0) {
            // write-through (agent-relaxed) store: visible at coherence
            // point, nothing dirty in L2, no wbl2 anywhere.
            if (e <= TABLE_N)
                __hip_atomic_store(&ws[e], q0 + B3, __ATOMIC_RELAXED,
                                   __HIP_MEMORY_SCOPE_AGENT);
            // order store -> flag within this wave; no barrier, no fence insn
            asm volatile("s_waitcnt vmcnt(0)" ::: "memory");
            __hip_atomic_store((unsigned int*)ws + FLAG_OFF + 8 * b + w,
                               FLAG_MAGIC, __ATOMIC_RELAXED,
                               __HIP_MEMORY_SCOPE_AGENT);
        }
        return;
    }

    // ---- consumer: 1 row per wave ----
    const int i = 8 * (b - PBLK) + w;
    const float4 pi = x4[i];                     // broadcast b128
    const float xi0 = pi.x, yi0 = pi.y, zi0 = pi.z;
    const float r0 = sqrtf(fmaf(xi0, xi0, fmaf(yi0, yi0, zi0 * zi0)));

    // xi MLP (hides behind the producer wait, which is the long pole)
    hbuf[w][lane] = sp_fast(fmaf(r0, w1s[lane], fmaf(t, w1s[64 + lane], b1s[lane])));
    float z0 = b2s[lane];
    #pragma unroll
    for (int k = 0; k < 64; k += 4) {
        float4 ha = *(const float4*)&hbuf[w][k];
        z0 = fmaf(ha.x, w2s[k * 64 + lane],       z0);
        z0 = fmaf(ha.y, w2s[(k + 1) * 64 + lane], z0);
        z0 = fmaf(ha.z, w2s[(k + 2) * 64 + lane], z0);
        z0 = fmaf(ha.w, w2s[(k + 3) * 64 + lane], z0);
    }
    float q0 = sp_fast(z0) * w3s[lane];
    #pragma unroll
    for (int off = 32; off > 0; off >>= 1) q0 += __shfl_xor(q0, off);
    const float fxi = q0 + B3;   // all lanes hold xi(|x_i|,t)

    // wait for the 520 producer-wave flags (expected ~0 wait)
    for (int f = tid; f < NFLAGS; f += 512) {
        const unsigned int* fl = (const unsigned int*)ws + FLAG_OFF + f;
        unsigned int v = __hip_atomic_load(fl, __ATOMIC_RELAXED,
                                           __HIP_MEMORY_SCOPE_AGENT);
        int it = 0;
        while (v != FLAG_MAGIC) {
            __builtin_amdgcn_s_sleep(1);   // polite backoff, no cache traffic
            v = ((++it & 31) == 0)
                  ? __hip_atomic_load(fl, __ATOMIC_ACQUIRE,
                                      __HIP_MEMORY_SCOPE_AGENT)
                  : __hip_atomic_load(fl, __ATOMIC_RELAXED,
                                      __HIP_MEMORY_SCOPE_AGENT);
        }
    }
    __syncthreads();
    {   // stage table via relaxed agent loads (producers' sc1 stores never
        // sat dirty in any L2 -> no invalidate needed)
        tab[tid] = __hip_atomic_load(&ws[tid], __ATOMIC_RELAXED,
                                     __HIP_MEMORY_SCOPE_AGENT);
        if (tid == 0)
            tab[512] = __hip_atomic_load(&ws[512], __ATOMIC_RELAXED,
                                         __HIP_MEMORY_SCOPE_AGENT);
    }
    __syncthreads();
    if (tid < 512) tab2[tid] = make_float2(tab[tid], tab[tid + 1]);
    __syncthreads();

    // pair loop, 1 row/wave: b128 x-read + single b64 table gather per iter
    float ax = 0.f, ay = 0.f, az = 0.f;
    const float scale = (float)TABLE_N / RMAX;     // 32
    #pragma unroll
    for (int it = 0; it < NPART / 64; ++it) {
        int j = it * 64 + lane;
        float4 pj = x4[j];
        float dx = xi0 - pj.x, dy = yi0 - pj.y, dz = zi0 - pj.z;
        float r = sqrtf(fmaf(dx, dx, fmaf(dy, dy, dz * dz)));
        float u = fminf(r * scale, (float)TABLE_N - 0.001f);
        int i0 = (int)u;
        float fr = u - (float)i0;
        float2 tt = tab2[i0];
        float f = fmaf(fr, tt.y - tt.x, tt.x);   // diagonal j==i: r=0 -> f*0=0
        ax = fmaf(f, dx, ax);
        ay = fmaf(f, dy, ay);
        az = fmaf(f, dz, az);
    }
    #pragma unroll
    for (int off = 32; off > 0; off >>= 1) {
        ax += __shfl_xor(ax, off);
        ay += __shfl_xor(ay, off);
        az += __shfl_xor(az, off);
    }
    if (lane == 0) {   // single writer of out; fxi never left registers
        out[3 * i]     = fmaf(fxi, xi0, ax);
        out[3 * i + 1] = fmaf(fxi, yi0, ay);
        out[3 * i + 2] = fmaf(fxi, zi0, az);
    }
}

extern "C" void kernel_launch(void* const* d_in, const int* in_sizes, int n_in,
                              void* d_out, int out_size, void* d_ws, size_t ws_size,
                              hipStream_t stream) {
    const float* x     = (const float*)d_in[0];
    const float* t     = (const float*)d_in[1];
    const float* xiW1  = (const float*)d_in[2];
    const float* xib1  = (const float*)d_in[3];
    const float* xiW2  = (const float*)d_in[4];
    const float* xib2  = (const float*)d_in[5];
    const float* xiW3  = (const float*)d_in[6];
    const float* xib3  = (const float*)d_in[7];
    const float* eW1   = (const float*)d_in[8];
    const float* eb1   = (const float*)d_in[9];
    const float* eW2   = (const float*)d_in[10];
    const float* eb2   = (const float*)d_in[11];
    const float* eW3   = (const float*)d_in[12];
    const float* eb3   = (const float*)d_in[13];
    float* out = (float*)d_out;
    float* ws  = (float*)d_ws;

    k_fused<<<PBLK + XBLK, 512, 0, stream>>>(
        x, t, xiW1, xib1, xiW2, xib2, xiW3, xib3,
        eW1, eb1, eW2, eb2, eW3, eb3, ws, out);
}